// Round 2
// baseline (636.548 us; speedup 1.0000x reference)
//
#include <hip/hip_runtime.h>
#include <cmath>

typedef float f4_t __attribute__((ext_vector_type(4)));
typedef long  l2_t __attribute__((ext_vector_type(2)));

#define B_TOTAL   65536
#define FTW_SCALE 1024.0f
#define INV_SCALE (1.0f/1024.0f)

__device__ __forceinline__ int pk8(float a, float b, float c, float d) {
    int v = __builtin_amdgcn_cvt_pk_fp8_f32(a, b, 0, false);
    return  __builtin_amdgcn_cvt_pk_fp8_f32(c, d, v, true);
}
__device__ __forceinline__ float clip01(float x) { return fminf(fmaxf(x, 0.f), 1.f); }

// ---------------------------------------------------------------------------
// Pack ft_w [1024][768] fp32 -> fp8(e4m3, x1024) in frag-pair order:
//   ws[(kk*32 + ncp)*1024 + lane*16 + half*8 + j]
//     = fp8( ftw[ col = ncp*32 + half*16 + (lane&15) ][ k = kk*32 + (lane>>4)*8 + j ] )
// One global_load_dwordx4 in the GEMM fetches 2 adjacent n-frags (16 B/lane).
// ---------------------------------------------------------------------------
__global__ void pack_ftw_kernel(const float* __restrict__ ftw, char* __restrict__ ws)
{
    int t    = blockIdx.x * 256 + threadIdx.x;   // 0..49151
    int lane = t & 63;
    int ncp  = (t >> 6) & 31;
    int kk   = t >> 11;                          // 0..23
    int nl = lane & 15, q = (lane >> 4) & 3;
    int k0 = kk * 32 + q * 8;
    const float* p0 = ftw + (size_t)(ncp * 32 + nl) * 768 + k0;
    const float* p1 = p0 + 16 * 768;
    float4 x0 = *(const float4*)p0;
    float4 x1 = *(const float4*)(p0 + 4);
    float4 y0 = *(const float4*)p1;
    float4 y1 = *(const float4*)(p1 + 4);
    int4 o;
    o.x = pk8(x0.x*FTW_SCALE, x0.y*FTW_SCALE, x0.z*FTW_SCALE, x0.w*FTW_SCALE);
    o.y = pk8(x1.x*FTW_SCALE, x1.y*FTW_SCALE, x1.z*FTW_SCALE, x1.w*FTW_SCALE);
    o.z = pk8(y0.x*FTW_SCALE, y0.y*FTW_SCALE, y0.z*FTW_SCALE, y0.w*FTW_SCALE);
    o.w = pk8(y1.x*FTW_SCALE, y1.y*FTW_SCALE, y1.z*FTW_SCALE, y1.w*FTW_SCALE);
    *(int4*)(ws + (size_t)t * 16) = o;
}

// ---------------------------------------------------------------------------
// Fused kernel. 1 block = 32 samples. A (white+black, fp8) staged in LDS in
// fragment order (conflict-free ds_read_b128). Each wave computes ALL 32
// samples x 256 columns (4 m-tiles per b-frag -> half the B traffic of R1),
// nb=4 column blocking, explicit 1-deep global B prefetch, no K-loop barriers.
// Epilogue: stm-blend + clip + l1 partial dot (VALU) -> shuffle-reduce -> tail.
// ---------------------------------------------------------------------------
__global__ __launch_bounds__(256, 3) void nnue_fused_kernel(
    const float* __restrict__ wf,  const float* __restrict__ bfeat,
    const float* __restrict__ stm, const char*  __restrict__ ftw8,
    const float* __restrict__ ftb, const float* __restrict__ l1w,
    const float* __restrict__ l1b, const float* __restrict__ l2w,
    const float* __restrict__ l2b, const float* __restrict__ l3w,
    const float* __restrict__ l3b, float* __restrict__ out)
{
    __shared__ char  Ald[24 * 2048];      // 48 KB: [(kk*2+p)*1024 + lane*16], p=0 w / 1 b
    __shared__ float l1part[4][32][8];    // 4 KB

    const int t    = threadIdx.x;
    const int lane = t & 63;
    const int wave = t >> 6;
    const int nl   = lane & 15;
    const int q    = (lane >> 4) & 3;
    const int s0   = blockIdx.x * 32;

    // ---- stage A: fp32 -> fp8 directly into fragment-pair layout ----
    {
        const int kpar = t >> 7;          // kk parity
        const int tt   = t & 127;
        const int p    = tt >> 6;         // 0 = white, 1 = black
        const int sl   = tt & 63;
        const int snl  = sl & 15, sq = (sl >> 4) & 3;
        const float* base = p ? bfeat : wf;
        const float* r0 = base + (size_t)(s0 + snl) * 768;
        const float* r1 = r0 + 16 * 768;
        char* dst = &Ald[p * 1024 + sl * 16];
        #pragma unroll 4
        for (int pass = 0; pass < 12; ++pass) {
            int kk = pass * 2 + kpar;
            int k0 = kk * 32 + sq * 8;
            float4 x0 = *(const float4*)(r0 + k0);
            float4 x1 = *(const float4*)(r0 + k0 + 4);
            float4 y0 = *(const float4*)(r1 + k0);
            float4 y1 = *(const float4*)(r1 + k0 + 4);
            int4 o;
            o.x = pk8(x0.x, x0.y, x0.z, x0.w);   // m-tile lo (rows 0-15)
            o.y = pk8(x1.x, x1.y, x1.z, x1.w);
            o.z = pk8(y0.x, y0.y, y0.z, y0.w);   // m-tile hi (rows 16-31)
            o.w = pk8(y1.x, y1.y, y1.z, y1.w);
            *(int4*)(dst + kk * 2048) = o;
        }
    }

    // stm for this lane's 8 rows (C/D layout row = q*4+r, +16 for hi tile)
    float s_lo[4], s_hi[4];
    #pragma unroll
    for (int r = 0; r < 4; ++r) {
        s_lo[r] = stm[s0 + q * 4 + r];
        s_hi[r] = stm[s0 + 16 + q * 4 + r];
    }

    __syncthreads();

    float pacc[2][4][8];                  // l1 partials [m-half][r][o]
    #pragma unroll
    for (int mh = 0; mh < 2; ++mh)
        #pragma unroll
        for (int r = 0; r < 4; ++r)
            #pragma unroll
            for (int o = 0; o < 8; ++o) pacc[mh][r][o] = 0.f;

    const char* ap = &Ald[lane * 16];

    #pragma unroll 1
    for (int ng = 0; ng < 4; ++ng) {
        f4_t aW0[4], aW1[4], aB0[4], aB1[4];
        #pragma unroll
        for (int nb = 0; nb < 4; ++nb) {
            aW0[nb] = (f4_t){0.f,0.f,0.f,0.f};
            aW1[nb] = (f4_t){0.f,0.f,0.f,0.f};
            aB0[nb] = (f4_t){0.f,0.f,0.f,0.f};
            aB1[nb] = (f4_t){0.f,0.f,0.f,0.f};
        }
        const char* bp = ftw8 + (size_t)(wave * 8 + ng * 2) * 1024 + lane * 16;
        l2_t bc0 = *(const l2_t*)(bp);
        l2_t bc1 = *(const l2_t*)(bp + 1024);

        #pragma unroll 2
        for (int kk = 0; kk < 24; ++kk) {
            l2_t bn0, bn1;
            if (kk < 23) {
                bn0 = *(const l2_t*)(bp + (size_t)(kk + 1) * 32768);
                bn1 = *(const l2_t*)(bp + (size_t)(kk + 1) * 32768 + 1024);
            }
            l2_t aw = *(const l2_t*)(ap + kk * 2048);          // w rows 0-15 | 16-31
            l2_t ab = *(const l2_t*)(ap + kk * 2048 + 1024);   // b rows 0-15 | 16-31

            aW0[0] = __builtin_amdgcn_mfma_f32_16x16x32_fp8_fp8(aw.x, bc0.x, aW0[0], 0,0,0);
            aW1[0] = __builtin_amdgcn_mfma_f32_16x16x32_fp8_fp8(aw.y, bc0.x, aW1[0], 0,0,0);
            aB0[0] = __builtin_amdgcn_mfma_f32_16x16x32_fp8_fp8(ab.x, bc0.x, aB0[0], 0,0,0);
            aB1[0] = __builtin_amdgcn_mfma_f32_16x16x32_fp8_fp8(ab.y, bc0.x, aB1[0], 0,0,0);
            aW0[1] = __builtin_amdgcn_mfma_f32_16x16x32_fp8_fp8(aw.x, bc0.y, aW0[1], 0,0,0);
            aW1[1] = __builtin_amdgcn_mfma_f32_16x16x32_fp8_fp8(aw.y, bc0.y, aW1[1], 0,0,0);
            aB0[1] = __builtin_amdgcn_mfma_f32_16x16x32_fp8_fp8(ab.x, bc0.y, aB0[1], 0,0,0);
            aB1[1] = __builtin_amdgcn_mfma_f32_16x16x32_fp8_fp8(ab.y, bc0.y, aB1[1], 0,0,0);
            aW0[2] = __builtin_amdgcn_mfma_f32_16x16x32_fp8_fp8(aw.x, bc1.x, aW0[2], 0,0,0);
            aW1[2] = __builtin_amdgcn_mfma_f32_16x16x32_fp8_fp8(aw.y, bc1.x, aW1[2], 0,0,0);
            aB0[2] = __builtin_amdgcn_mfma_f32_16x16x32_fp8_fp8(ab.x, bc1.x, aB0[2], 0,0,0);
            aB1[2] = __builtin_amdgcn_mfma_f32_16x16x32_fp8_fp8(ab.y, bc1.x, aB1[2], 0,0,0);
            aW0[3] = __builtin_amdgcn_mfma_f32_16x16x32_fp8_fp8(aw.x, bc1.y, aW0[3], 0,0,0);
            aW1[3] = __builtin_amdgcn_mfma_f32_16x16x32_fp8_fp8(aw.y, bc1.y, aW1[3], 0,0,0);
            aB0[3] = __builtin_amdgcn_mfma_f32_16x16x32_fp8_fp8(ab.x, bc1.y, aB0[3], 0,0,0);
            aB1[3] = __builtin_amdgcn_mfma_f32_16x16x32_fp8_fp8(ab.y, bc1.y, aB1[3], 0,0,0);

            if (kk < 23) { bc0 = bn0; bc1 = bn1; }
        }

        // epilogue: blend + clip + l1 partial dot over this ng's 64 columns
        #pragma unroll
        for (int nb = 0; nb < 4; ++nb) {
            int col = wave * 256 + ng * 64 + nb * 16 + nl;
            float bias = ftb[col];
            const float* l1c = l1w + col;
            float lo[8], hi[8];
            #pragma unroll
            for (int o = 0; o < 8; ++o) {
                lo[o] = l1c[o * 2048];
                hi[o] = l1c[o * 2048 + 1024];
            }
            #pragma unroll
            for (int r = 0; r < 4; ++r) {
                float w0 = fmaf(aW0[nb][r], INV_SCALE, bias);
                float b0 = fmaf(aB0[nb][r], INV_SCALE, bias);
                float w1 = fmaf(aW1[nb][r], INV_SCALE, bias);
                float b1 = fmaf(aB1[nb][r], INV_SCALE, bias);
                float d0 = w0 - b0, d1 = w1 - b1;
                float f0 = clip01(fmaf( s_lo[r], d0, b0));   // stm*w + (1-stm)*b
                float g0 = clip01(fmaf(-s_lo[r], d0, w0));   // stm*b + (1-stm)*w
                float f1 = clip01(fmaf( s_hi[r], d1, b1));
                float g1 = clip01(fmaf(-s_hi[r], d1, w1));
                #pragma unroll
                for (int o = 0; o < 8; ++o) {
                    pacc[0][r][o] = fmaf(f0, lo[o], fmaf(g0, hi[o], pacc[0][r][o]));
                    pacc[1][r][o] = fmaf(f1, lo[o], fmaf(g1, hi[o], pacc[1][r][o]));
                }
            }
        }
    }

    // reduce partials across the 16 column-lanes (low 4 lane bits)
    #pragma unroll
    for (int m = 1; m < 16; m <<= 1)
        #pragma unroll
        for (int mh = 0; mh < 2; ++mh)
            #pragma unroll
            for (int r = 0; r < 4; ++r)
                #pragma unroll
                for (int o = 0; o < 8; ++o)
                    pacc[mh][r][o] += __shfl_xor(pacc[mh][r][o], m);

    if (nl == 0) {
        #pragma unroll
        for (int mh = 0; mh < 2; ++mh)
            #pragma unroll
            for (int r = 0; r < 4; ++r)
                #pragma unroll
                for (int o = 0; o < 8; ++o)
                    l1part[wave][mh * 16 + q * 4 + r][o] = pacc[mh][r][o];
    }
    __syncthreads();

    // tail MLP: l1 bias+clip -> l2 -> l3 -> sigmoid
    if (t < 32) {
        float v[8];
        #pragma unroll
        for (int o = 0; o < 8; ++o)
            v[o] = clip01(l1part[0][t][o] + l1part[1][t][o] +
                          l1part[2][t][o] + l1part[3][t][o] + l1b[o]);
        float raw = l3b[0];
        #pragma unroll
        for (int u = 0; u < 32; ++u) {
            float h = l2b[u];
            #pragma unroll
            for (int o = 0; o < 8; ++o) h = fmaf(v[o], l2w[u * 8 + o], h);
            h = clip01(h);
            raw = fmaf(h, l3w[u], raw);
        }
        out[s0 + t]           = 1.0f / (1.0f + expf(-raw));
        out[B_TOTAL + s0 + t] = raw;
    }
}

extern "C" void kernel_launch(void* const* d_in, const int* in_sizes, int n_in,
                              void* d_out, int out_size, void* d_ws, size_t ws_size,
                              hipStream_t stream)
{
    const float* wf  = (const float*)d_in[0];
    const float* bf  = (const float*)d_in[1];
    const float* stm = (const float*)d_in[2];
    const float* ftw = (const float*)d_in[3];
    const float* ftb = (const float*)d_in[4];
    const float* l1w = (const float*)d_in[5];
    const float* l1b = (const float*)d_in[6];
    const float* l2w = (const float*)d_in[7];
    const float* l2b = (const float*)d_in[8];
    const float* l3w = (const float*)d_in[9];
    const float* l3b = (const float*)d_in[10];
    char* ws8 = (char*)d_ws;   // 768 KB packed fp8 ft_w

    hipLaunchKernelGGL(pack_ftw_kernel, dim3(192), dim3(256), 0, stream, ftw, ws8);
    hipLaunchKernelGGL(nnue_fused_kernel, dim3(2048), dim3(256), 0, stream,
                       wf, bf, stm, ws8, ftb, l1w, l1b, l2w, l2b, l3w, l3b,
                       (float*)d_out);
}

// Round 3
// 597.406 us; speedup vs baseline: 1.0655x; 1.0655x over previous
//
#include <hip/hip_runtime.h>
#include <cmath>

typedef float f4_t __attribute__((ext_vector_type(4)));
typedef float f2_t __attribute__((ext_vector_type(2)));
typedef long  l2_t __attribute__((ext_vector_type(2)));

#define B_TOTAL   65536
#define FTW_SCALE 1024.0f
#define INV_SCALE (1.0f/1024.0f)

__device__ __forceinline__ int pk8(float a, float b, float c, float d) {
    int v = __builtin_amdgcn_cvt_pk_fp8_f32(a, b, 0, false);
    return  __builtin_amdgcn_cvt_pk_fp8_f32(c, d, v, true);
}
__device__ __forceinline__ float clip01(float x) { return fminf(fmaxf(x, 0.f), 1.f); }

// ---------------------------------------------------------------------------
// Pack ft_w [1024][768] fp32 -> fp8(e4m3, x1024) in frag-pair order:
//   ws[(kk*32 + ncp)*1024 + lane*16]  holds cols ncp*32+[0,32) for k-chunk kk
//   bytes 0-7 = cols +[0,16) frag, bytes 8-15 = cols +[16,32) frag.
// ---------------------------------------------------------------------------
__global__ void pack_ftw_kernel(const float* __restrict__ ftw, char* __restrict__ ws)
{
    int t    = blockIdx.x * 256 + threadIdx.x;   // 0..49151
    int lane = t & 63;
    int ncp  = (t >> 6) & 31;
    int kk   = t >> 11;                          // 0..23
    int nl = lane & 15, q = (lane >> 4) & 3;
    int k0 = kk * 32 + q * 8;
    const float* p0 = ftw + (size_t)(ncp * 32 + nl) * 768 + k0;
    const float* p1 = p0 + 16 * 768;
    float4 x0 = *(const float4*)p0;
    float4 x1 = *(const float4*)(p0 + 4);
    float4 y0 = *(const float4*)p1;
    float4 y1 = *(const float4*)(p1 + 4);
    int4 o;
    o.x = pk8(x0.x*FTW_SCALE, x0.y*FTW_SCALE, x0.z*FTW_SCALE, x0.w*FTW_SCALE);
    o.y = pk8(x1.x*FTW_SCALE, x1.y*FTW_SCALE, x1.z*FTW_SCALE, x1.w*FTW_SCALE);
    o.z = pk8(y0.x*FTW_SCALE, y0.y*FTW_SCALE, y0.z*FTW_SCALE, y0.w*FTW_SCALE);
    o.w = pk8(y1.x*FTW_SCALE, y1.y*FTW_SCALE, y1.z*FTW_SCALE, y1.w*FTW_SCALE);
    *(int4*)(ws + (size_t)t * 16) = o;
}

// ---------------------------------------------------------------------------
// Fused kernel. 1 block = 32 samples; A (w+b, fp8) in LDS fragment order.
// Each wave: all 32 samples (4 m-tiles) x its 256 columns, nb=2 col blocking
// (32 acc VGPRs, no spill), depth-2 global B prefetch, no K-loop barriers.
// Epilogue: blend+clip+l1 partial dot (packed f2 fma) -> shuffle -> tail MLP.
// ---------------------------------------------------------------------------
__global__ __launch_bounds__(256, 3) void nnue_fused_kernel(
    const float* __restrict__ wf,  const float* __restrict__ bfeat,
    const float* __restrict__ stm, const char*  __restrict__ ftw8,
    const float* __restrict__ ftb, const float* __restrict__ l1w,
    const float* __restrict__ l1b, const float* __restrict__ l2w,
    const float* __restrict__ l2b, const float* __restrict__ l3w,
    const float* __restrict__ l3b, float* __restrict__ out)
{
    __shared__ char  Ald[24 * 2048];      // 48 KB: [(kk*2+p)*1024 + lane*16]
    __shared__ float l1part[4][32][8];    // 4 KB

    const int t    = threadIdx.x;
    const int lane = t & 63;
    const int wave = t >> 6;
    const int nl   = lane & 15;
    const int q    = (lane >> 4) & 3;
    const int s0   = blockIdx.x * 32;

    // ---- stage A: fp32 -> fp8 directly into fragment-pair layout ----
    {
        const int kpar = t >> 7;
        const int tt   = t & 127;
        const int p    = tt >> 6;         // 0 = white, 1 = black
        const int sl   = tt & 63;
        const int snl  = sl & 15, sq = (sl >> 4) & 3;
        const float* base = p ? bfeat : wf;
        const float* r0 = base + (size_t)(s0 + snl) * 768;
        const float* r1 = r0 + 16 * 768;
        char* dst = &Ald[p * 1024 + sl * 16];
        #pragma unroll 4
        for (int pass = 0; pass < 12; ++pass) {
            int kk = pass * 2 + kpar;
            int k0 = kk * 32 + sq * 8;
            float4 x0 = *(const float4*)(r0 + k0);
            float4 x1 = *(const float4*)(r0 + k0 + 4);
            float4 y0 = *(const float4*)(r1 + k0);
            float4 y1 = *(const float4*)(r1 + k0 + 4);
            int4 o;
            o.x = pk8(x0.x, x0.y, x0.z, x0.w);   // rows 0-15
            o.y = pk8(x1.x, x1.y, x1.z, x1.w);
            o.z = pk8(y0.x, y0.y, y0.z, y0.w);   // rows 16-31
            o.w = pk8(y1.x, y1.y, y1.z, y1.w);
            *(int4*)(dst + kk * 2048) = o;
        }
    }

    float s_lo[4], s_hi[4];
    #pragma unroll
    for (int r = 0; r < 4; ++r) {
        s_lo[r] = stm[s0 + q * 4 + r];
        s_hi[r] = stm[s0 + 16 + q * 4 + r];
    }

    __syncthreads();

    f2_t pacc[2][4][4];                   // l1 partials [m-half][r][o-pair]
    #pragma unroll
    for (int mh = 0; mh < 2; ++mh)
        #pragma unroll
        for (int r = 0; r < 4; ++r)
            #pragma unroll
            for (int i = 0; i < 4; ++i) pacc[mh][r][i] = (f2_t){0.f, 0.f};

    const char* ap = &Ald[lane * 16];

    #pragma unroll 1
    for (int ng = 0; ng < 8; ++ng) {
        // acc[m][n]: m = {w-lo, w-hi, b-lo, b-hi} sample tiles, n = col frag
        f4_t acc[4][2];
        #pragma unroll
        for (int m = 0; m < 4; ++m) {
            acc[m][0] = (f4_t){0.f,0.f,0.f,0.f};
            acc[m][1] = (f4_t){0.f,0.f,0.f,0.f};
        }
        const char* bp = ftw8 + (size_t)(wave * 8 + ng) * 1024 + (size_t)lane * 16;
        l2_t bc0 = *(const l2_t*)(bp);
        l2_t bc1 = *(const l2_t*)(bp + 32768);

        #pragma unroll 2
        for (int kg = 0; kg < 12; ++kg) {
            int pf0 = (kg < 11) ? (2 * kg + 2) : 22;
            int pf1 = (kg < 11) ? (2 * kg + 3) : 23;
            l2_t bn0 = *(const l2_t*)(bp + (size_t)pf0 * 32768);
            l2_t bn1 = *(const l2_t*)(bp + (size_t)pf1 * 32768);

            l2_t aw = *(const l2_t*)(ap + (2 * kg) * 2048);
            l2_t ab = *(const l2_t*)(ap + (2 * kg) * 2048 + 1024);
            acc[0][0] = __builtin_amdgcn_mfma_f32_16x16x32_fp8_fp8(aw.x, bc0.x, acc[0][0], 0,0,0);
            acc[1][0] = __builtin_amdgcn_mfma_f32_16x16x32_fp8_fp8(aw.y, bc0.x, acc[1][0], 0,0,0);
            acc[2][0] = __builtin_amdgcn_mfma_f32_16x16x32_fp8_fp8(ab.x, bc0.x, acc[2][0], 0,0,0);
            acc[3][0] = __builtin_amdgcn_mfma_f32_16x16x32_fp8_fp8(ab.y, bc0.x, acc[3][0], 0,0,0);
            acc[0][1] = __builtin_amdgcn_mfma_f32_16x16x32_fp8_fp8(aw.x, bc0.y, acc[0][1], 0,0,0);
            acc[1][1] = __builtin_amdgcn_mfma_f32_16x16x32_fp8_fp8(aw.y, bc0.y, acc[1][1], 0,0,0);
            acc[2][1] = __builtin_amdgcn_mfma_f32_16x16x32_fp8_fp8(ab.x, bc0.y, acc[2][1], 0,0,0);
            acc[3][1] = __builtin_amdgcn_mfma_f32_16x16x32_fp8_fp8(ab.y, bc0.y, acc[3][1], 0,0,0);

            l2_t aw2 = *(const l2_t*)(ap + (2 * kg + 1) * 2048);
            l2_t ab2 = *(const l2_t*)(ap + (2 * kg + 1) * 2048 + 1024);
            acc[0][0] = __builtin_amdgcn_mfma_f32_16x16x32_fp8_fp8(aw2.x, bc1.x, acc[0][0], 0,0,0);
            acc[1][0] = __builtin_amdgcn_mfma_f32_16x16x32_fp8_fp8(aw2.y, bc1.x, acc[1][0], 0,0,0);
            acc[2][0] = __builtin_amdgcn_mfma_f32_16x16x32_fp8_fp8(ab2.x, bc1.x, acc[2][0], 0,0,0);
            acc[3][0] = __builtin_amdgcn_mfma_f32_16x16x32_fp8_fp8(ab2.y, bc1.x, acc[3][0], 0,0,0);
            acc[0][1] = __builtin_amdgcn_mfma_f32_16x16x32_fp8_fp8(aw2.x, bc1.y, acc[0][1], 0,0,0);
            acc[1][1] = __builtin_amdgcn_mfma_f32_16x16x32_fp8_fp8(aw2.y, bc1.y, acc[1][1], 0,0,0);
            acc[2][1] = __builtin_amdgcn_mfma_f32_16x16x32_fp8_fp8(ab2.x, bc1.y, acc[2][1], 0,0,0);
            acc[3][1] = __builtin_amdgcn_mfma_f32_16x16x32_fp8_fp8(ab2.y, bc1.y, acc[3][1], 0,0,0);

            bc0 = bn0; bc1 = bn1;
        }

        // epilogue: blend + clip + l1 partial dot over this ng's 32 columns
        #pragma unroll
        for (int nb = 0; nb < 2; ++nb) {
            int col = wave * 256 + ng * 32 + nb * 16 + nl;
            float bias = ftb[col];
            const float* l1c = l1w + col;
            f2_t lo2[4], hi2[4];
            #pragma unroll
            for (int i = 0; i < 4; ++i) {
                lo2[i] = (f2_t){l1c[(2*i) * 2048],        l1c[(2*i+1) * 2048]};
                hi2[i] = (f2_t){l1c[(2*i) * 2048 + 1024], l1c[(2*i+1) * 2048 + 1024]};
            }
            #pragma unroll
            for (int r = 0; r < 4; ++r) {
                float w0 = fmaf(acc[0][nb][r], INV_SCALE, bias);
                float w1 = fmaf(acc[1][nb][r], INV_SCALE, bias);
                float b0 = fmaf(acc[2][nb][r], INV_SCALE, bias);
                float b1 = fmaf(acc[3][nb][r], INV_SCALE, bias);
                float d0 = w0 - b0, d1 = w1 - b1;
                float f0 = clip01(fmaf( s_lo[r], d0, b0));   // stm*w + (1-stm)*b
                float g0 = clip01(fmaf(-s_lo[r], d0, w0));   // stm*b + (1-stm)*w
                float f1 = clip01(fmaf( s_hi[r], d1, b1));
                float g1 = clip01(fmaf(-s_hi[r], d1, w1));
                #pragma unroll
                for (int i = 0; i < 4; ++i) {
                    pacc[0][r][i] += f0 * lo2[i] + g0 * hi2[i];
                    pacc[1][r][i] += f1 * lo2[i] + g1 * hi2[i];
                }
            }
        }
    }

    // reduce partials across the 16 column-lanes
    #pragma unroll
    for (int m = 1; m < 16; m <<= 1)
        #pragma unroll
        for (int mh = 0; mh < 2; ++mh)
            #pragma unroll
            for (int r = 0; r < 4; ++r)
                #pragma unroll
                for (int i = 0; i < 4; ++i) {
                    pacc[mh][r][i].x += __shfl_xor(pacc[mh][r][i].x, m);
                    pacc[mh][r][i].y += __shfl_xor(pacc[mh][r][i].y, m);
                }

    if (nl == 0) {
        #pragma unroll
        for (int mh = 0; mh < 2; ++mh)
            #pragma unroll
            for (int r = 0; r < 4; ++r)
                #pragma unroll
                for (int i = 0; i < 4; ++i) {
                    l1part[wave][mh * 16 + q * 4 + r][2*i]   = pacc[mh][r][i].x;
                    l1part[wave][mh * 16 + q * 4 + r][2*i+1] = pacc[mh][r][i].y;
                }
    }
    __syncthreads();

    // tail MLP: l1 bias+clip -> l2 -> l3 -> sigmoid
    if (t < 32) {
        float v[8];
        #pragma unroll
        for (int o = 0; o < 8; ++o)
            v[o] = clip01(l1part[0][t][o] + l1part[1][t][o] +
                          l1part[2][t][o] + l1part[3][t][o] + l1b[o]);
        float raw = l3b[0];
        #pragma unroll
        for (int u = 0; u < 32; ++u) {
            float h = l2b[u];
            #pragma unroll
            for (int o = 0; o < 8; ++o) h = fmaf(v[o], l2w[u * 8 + o], h);
            h = clip01(h);
            raw = fmaf(h, l3w[u], raw);
        }
        out[s0 + t]           = 1.0f / (1.0f + expf(-raw));
        out[B_TOTAL + s0 + t] = raw;
    }
}

extern "C" void kernel_launch(void* const* d_in, const int* in_sizes, int n_in,
                              void* d_out, int out_size, void* d_ws, size_t ws_size,
                              hipStream_t stream)
{
    const float* wf  = (const float*)d_in[0];
    const float* bf  = (const float*)d_in[1];
    const float* stm = (const float*)d_in[2];
    const float* ftw = (const float*)d_in[3];
    const float* ftb = (const float*)d_in[4];
    const float* l1w = (const float*)d_in[5];
    const float* l1b = (const float*)d_in[6];
    const float* l2w = (const float*)d_in[7];
    const float* l2b = (const float*)d_in[8];
    const float* l3w = (const float*)d_in[9];
    const float* l3b = (const float*)d_in[10];
    char* ws8 = (char*)d_ws;   // 768 KB packed fp8 ft_w

    hipLaunchKernelGGL(pack_ftw_kernel, dim3(192), dim3(256), 0, stream, ftw, ws8);
    hipLaunchKernelGGL(nnue_fused_kernel, dim3(2048), dim3(256), 0, stream,
                       wf, bf, stm, ws8, ftb, l1w, l1b, l2w, l2b, l3w, l3b,
                       (float*)d_out);
}